// Round 3
// baseline (149.471 us; speedup 1.0000x reference)
//
#include <hip/hip_runtime.h>
#include <cstdint>
#include <cstddef>

#define NN 8192
#define INF 512
#define OUTF 64
#define ALPHA 0.2f
#define NSPLIT 8
#define JSPLIT (NN / NSPLIT)   // 1024

typedef short bf16x8 __attribute__((ext_vector_type(8)));
typedef float f32x4 __attribute__((ext_vector_type(4)));

static __device__ inline unsigned short f2bf(float f) {
    unsigned u = __builtin_bit_cast(unsigned, f);
    unsigned r = (u + 0x7FFFu + ((u >> 16) & 1u)) >> 16;
    return (unsigned short)r;
}

// ---------------------------------------------------------------------------
// Kernel 1: Wh = x @ W (fp32), then:
//   WhbT[c][i] = bf16(Wh[i][c])   (transposed bf16 copy for MFMA A-operand)
//   s1[i] = Wh[i][:] . a[0:64],  s2[i] = Wh[i][:] . a[64:128]
// 512 blocks x 256 threads; each block computes 16 rows of Wh.
// ---------------------------------------------------------------------------
__global__ __launch_bounds__(256) void k1_gemm(
    const float* __restrict__ x, const float* __restrict__ W,
    const float* __restrict__ a, unsigned short* __restrict__ WhbT,
    float* __restrict__ s1, float* __restrict__ s2)
{
    __shared__ float xs[16][512];   // 32 KB
    const int tid = threadIdx.x;
    const int i0  = blockIdx.x * 16;

    // stage x tile: 16 rows x 512 f32 = 2048 float4
    #pragma unroll
    for (int k = 0; k < 8; ++k) {
        int f  = tid + 256 * k;
        int r  = f >> 7;
        int c4 = f & 127;
        *(float4*)&xs[r][c4 * 4] =
            *(const float4*)&x[(size_t)(i0 + r) * INF + c4 * 4];
    }
    __syncthreads();

    const int w = tid >> 6;    // wave 0..3 -> rows 4w..4w+3
    const int c = tid & 63;    // output column
    float acc[4] = {0.f, 0.f, 0.f, 0.f};
    const float* Wc = W + c;

    for (int kk = 0; kk < 128; ++kk) {
        float4 xv[4];
        #pragma unroll
        for (int q = 0; q < 4; ++q)
            xv[q] = *(const float4*)&xs[4 * w + q][kk * 4];
        float wv[4];
        #pragma unroll
        for (int e = 0; e < 4; ++e)
            wv[e] = Wc[(kk * 4 + e) * OUTF];
        #pragma unroll
        for (int q = 0; q < 4; ++q) {
            acc[q] = fmaf(xv[q].x, wv[0], acc[q]);
            acc[q] = fmaf(xv[q].y, wv[1], acc[q]);
            acc[q] = fmaf(xv[q].z, wv[2], acc[q]);
            acc[q] = fmaf(xv[q].w, wv[3], acc[q]);
        }
    }

    // s1/s2 wave reductions (64 lanes, one row per reduction)
    const float a1c = a[c];
    const float a2c = a[64 + c];
    #pragma unroll
    for (int q = 0; q < 4; ++q) {
        float v1 = acc[q] * a1c;
        float v2 = acc[q] * a2c;
        #pragma unroll
        for (int m = 32; m; m >>= 1) {
            v1 += __shfl_xor(v1, m, 64);
            v2 += __shfl_xor(v2, m, 64);
        }
        if (c == 0) {
            s1[i0 + 4 * w + q] = v1;
            s2[i0 + 4 * w + q] = v2;
        }
    }

    // transposed bf16 store: WhbT[c][i0+4w+q], 4 consecutive j -> one 8B store
    ushort4 pk;
    pk.x = f2bf(acc[0]); pk.y = f2bf(acc[1]);
    pk.z = f2bf(acc[2]); pk.w = f2bf(acc[3]);
    *(ushort4*)&WhbT[(size_t)c * NN + i0 + 4 * w] = pk;
}

// ---------------------------------------------------------------------------
// Kernel 2: fused masked-softmax attention — BARRIER-FREE, wave-independent.
//   Each wave owns a 16-row i-tile x 1024-j split. P is produced directly in
//   the MFMA B-fragment register layout (lane l: row i=l&15, j=(l>>4)*8+e),
//   so there is no LDS and no __syncthreads -> no vmcnt(0) drains; the
//   compiler pipelines adj loads freely across iterations.
//   4096 wave-tasks = 1024 blocks x 4 waves (16 waves/CU).
// ---------------------------------------------------------------------------
__global__ __launch_bounds__(256) void k2_attn(
    const int* __restrict__ adj, const unsigned short* __restrict__ WhbT,
    const float* __restrict__ s1g, const float* __restrict__ s2g,
    float* __restrict__ Opart, float* __restrict__ lpart)
{
    const int tid   = threadIdx.x;
    const int l     = tid & 63;
    const int w     = tid >> 6;
    const int task  = blockIdx.x * 4 + w;      // 0..4095
    const int i0    = (task >> 3) * 16;
    const int split = task & 7;
    const int jbase = split * JSPLIT;

    const int il  = l & 15;
    const int kg8 = (l >> 4) * 8;

    const float s1v = s1g[i0 + il];

    const int*            ap = adj  + (size_t)(i0 + il) * NN + jbase + kg8;
    const float*          sp = s2g  + jbase + kg8;
    const unsigned short* Ab = WhbT + (size_t)il * NN + jbase + kg8;

    f32x4 acc0 = {0.f,0.f,0.f,0.f}, acc1 = {0.f,0.f,0.f,0.f};
    f32x4 acc2 = {0.f,0.f,0.f,0.f}, acc3 = {0.f,0.f,0.f,0.f};
    float la = 0.f;

#define SC(S2c, M) ((M) ? __expf(fmaxf(s1v + (S2c), ALPHA * (s1v + (S2c)))) : 0.f)

    for (int t = 0; t < JSPLIT / 32; ++t) {
        const int jo = t * 32;

        int4   m0 = *(const int4*)(ap + jo);
        int4   m1 = *(const int4*)(ap + jo + 4);
        float4 sa = *(const float4*)(sp + jo);
        float4 sb = *(const float4*)(sp + jo + 4);
        bf16x8 A0 = *(const bf16x8*)(Ab + jo);
        bf16x8 A1 = *(const bf16x8*)(Ab + (size_t)16 * NN + jo);
        bf16x8 A2 = *(const bf16x8*)(Ab + (size_t)32 * NN + jo);
        bf16x8 A3 = *(const bf16x8*)(Ab + (size_t)48 * NN + jo);

        float p0 = SC(sa.x, m0.x), p1 = SC(sa.y, m0.y);
        float p2 = SC(sa.z, m0.z), p3 = SC(sa.w, m0.w);
        float p4 = SC(sb.x, m1.x), p5 = SC(sb.y, m1.y);
        float p6 = SC(sb.z, m1.z), p7 = SC(sb.w, m1.w);
        la += ((p0 + p1) + (p2 + p3)) + ((p4 + p5) + (p6 + p7));

        uint4 bw;
        asm("v_cvt_pk_bf16_f32 %0, %1, %2" : "=v"(bw.x) : "v"(p0), "v"(p1));
        asm("v_cvt_pk_bf16_f32 %0, %1, %2" : "=v"(bw.y) : "v"(p2), "v"(p3));
        asm("v_cvt_pk_bf16_f32 %0, %1, %2" : "=v"(bw.z) : "v"(p4), "v"(p5));
        asm("v_cvt_pk_bf16_f32 %0, %1, %2" : "=v"(bw.w) : "v"(p6), "v"(p7));
        bf16x8 B = __builtin_bit_cast(bf16x8, bw);

        acc0 = __builtin_amdgcn_mfma_f32_16x16x32_bf16(A0, B, acc0, 0, 0, 0);
        acc1 = __builtin_amdgcn_mfma_f32_16x16x32_bf16(A1, B, acc1, 0, 0, 0);
        acc2 = __builtin_amdgcn_mfma_f32_16x16x32_bf16(A2, B, acc2, 0, 0, 0);
        acc3 = __builtin_amdgcn_mfma_f32_16x16x32_bf16(A3, B, acc3, 0, 0, 0);
    }
#undef SC

    // row-sum: lanes {il, il+16, il+32, il+48} hold partials for row i0+il
    la += __shfl_xor(la, 16, 64);
    la += __shfl_xor(la, 32, 64);
    if (kg8 == 0)
        lpart[(size_t)split * NN + i0 + il] = la;

    // numerator partials: acc_q[r] = out^T[n = q*16 + (l>>4)*4 + r][i = i0+il]
    const int nn = (l >> 4) * 4;
    float* Orow = Opart + ((size_t)split * NN + i0 + il) * OUTF + nn;
    *(float4*)(Orow)      = *(float4*)&acc0;
    *(float4*)(Orow + 16) = *(float4*)&acc1;
    *(float4*)(Orow + 32) = *(float4*)&acc2;
    *(float4*)(Orow + 48) = *(float4*)&acc3;
}

// ---------------------------------------------------------------------------
// Kernel 3: combine the 8 j-split partials and normalize.
// ---------------------------------------------------------------------------
__global__ __launch_bounds__(256) void k3_combine(
    const float* __restrict__ Opart, const float* __restrict__ lpart,
    float* __restrict__ out)
{
    const int f4 = blockIdx.x * 256 + threadIdx.x;   // 0..131071
    const int i  = f4 >> 4;

    float4 r = {0.f, 0.f, 0.f, 0.f};
    float  lsum = 0.f;
    #pragma unroll
    for (int s = 0; s < NSPLIT; ++s) {
        float4 o = *(const float4*)&Opart[(size_t)s * NN * OUTF + (size_t)f4 * 4];
        r.x += o.x; r.y += o.y; r.z += o.z; r.w += o.w;
        lsum += lpart[(size_t)s * NN + i];
    }
    float inv = 1.0f / lsum;
    r.x *= inv; r.y *= inv; r.z *= inv; r.w *= inv;
    *(float4*)&out[(size_t)f4 * 4] = r;
}

extern "C" void kernel_launch(void* const* d_in, const int* in_sizes, int n_in,
                              void* d_out, int out_size, void* d_ws, size_t ws_size,
                              hipStream_t stream) {
    const float* x   = (const float*)d_in[0];
    const int*   adj = (const int*)d_in[1];
    const float* W   = (const float*)d_in[2];
    const float* a   = (const float*)d_in[3];
    float* out = (float*)d_out;

    char* ws = (char*)d_ws;
    unsigned short* WhbT = (unsigned short*)ws;                     // 1 MB
    float* s1    = (float*)(ws + (1 << 20));                        // 32 KB
    float* s2    = (float*)(ws + (1 << 20) + 32768);                // 32 KB
    float* lpart = (float*)(ws + (1 << 20) + 65536);                // 256 KB
    float* Opart = (float*)(ws + (1 << 20) + 65536 + 262144);       // 16 MB

    k1_gemm<<<512, 256, 0, stream>>>(x, W, a, WhbT, s1, s2);
    k2_attn<<<1024, 256, 0, stream>>>(adj, WhbT, s1, s2, Opart, lpart);
    k3_combine<<<512, 256, 0, stream>>>(Opart, lpart, out);
}

// Round 4
// 115.968 us; speedup vs baseline: 1.2889x; 1.2889x over previous
//
#include <hip/hip_runtime.h>
#include <cstdint>
#include <cstddef>

#define NN 8192
#define INF 512
#define OUTF 64
#define ALPHA 0.2f
#define NSPLIT 16
#define JSPLIT (NN / NSPLIT)   // 512
#define NW32 (NN / 32)         // 256 mask words per row

typedef short bf16x8 __attribute__((ext_vector_type(8)));
typedef float f32x4 __attribute__((ext_vector_type(4)));

static __device__ inline unsigned short f2bf(float f) {
    unsigned u = __builtin_bit_cast(unsigned, f);
    unsigned r = (u + 0x7FFFu + ((u >> 16) & 1u)) >> 16;
    return (unsigned short)r;
}

// ---------------------------------------------------------------------------
// Kernel 0: pack adj (int32 0/1) into a bitmask, 32 j per uint32.
// Each thread packs 32 consecutive ints (128 B contiguous read, 4 B write).
// 8192 blocks x 256 threads. Pure streaming: the one unavoidable 268 MB read.
// ---------------------------------------------------------------------------
__global__ __launch_bounds__(256) void k0_mask(
    const int* __restrict__ adj, unsigned* __restrict__ mask)
{
    const size_t gid = (size_t)blockIdx.x * 256 + threadIdx.x;   // 0..2M-1
    const int* p = adj + gid * 32;
    unsigned m = 0;
    #pragma unroll
    for (int k = 0; k < 8; ++k) {
        int4 v = *(const int4*)(p + 4 * k);
        m |= (v.x != 0 ? 1u : 0u) << (4 * k);
        m |= (v.y != 0 ? 1u : 0u) << (4 * k + 1);
        m |= (v.z != 0 ? 1u : 0u) << (4 * k + 2);
        m |= (v.w != 0 ? 1u : 0u) << (4 * k + 3);
    }
    mask[gid] = m;
}

// ---------------------------------------------------------------------------
// Kernel 1: Wh = x @ W (fp32). Outputs:
//   Asw  - Wh in MFMA A-fragment-swizzled bf16 layout:
//          Asw[(g*256 + jt)*512 + (r + 16*sub)*8 + e] = Wh[jt*32+sub*8+e][g*16+r]
//          so k2's A-load is a dense 1 KB wave load.
//   s1[i] = Wh[i][:] . a[0:64],  s2[i] = Wh[i][:] . a[64:128]
// 512 blocks x 256 threads; each block computes 16 rows of Wh.
// ---------------------------------------------------------------------------
__global__ __launch_bounds__(256) void k1_gemm(
    const float* __restrict__ x, const float* __restrict__ W,
    const float* __restrict__ a, unsigned short* __restrict__ Asw,
    float* __restrict__ s1, float* __restrict__ s2)
{
    __shared__ float xs[16][512];   // 32 KB
    const int tid = threadIdx.x;
    const int i0  = blockIdx.x * 16;

    #pragma unroll
    for (int k = 0; k < 8; ++k) {
        int f  = tid + 256 * k;
        int r  = f >> 7;
        int c4 = f & 127;
        *(float4*)&xs[r][c4 * 4] =
            *(const float4*)&x[(size_t)(i0 + r) * INF + c4 * 4];
    }
    __syncthreads();

    const int w = tid >> 6;    // wave 0..3 -> rows 4w..4w+3
    const int c = tid & 63;    // output column
    float acc[4] = {0.f, 0.f, 0.f, 0.f};
    const float* Wc = W + c;

    for (int kk = 0; kk < 128; ++kk) {
        float4 xv[4];
        #pragma unroll
        for (int q = 0; q < 4; ++q)
            xv[q] = *(const float4*)&xs[4 * w + q][kk * 4];
        float wv[4];
        #pragma unroll
        for (int e = 0; e < 4; ++e)
            wv[e] = Wc[(kk * 4 + e) * OUTF];
        #pragma unroll
        for (int q = 0; q < 4; ++q) {
            acc[q] = fmaf(xv[q].x, wv[0], acc[q]);
            acc[q] = fmaf(xv[q].y, wv[1], acc[q]);
            acc[q] = fmaf(xv[q].z, wv[2], acc[q]);
            acc[q] = fmaf(xv[q].w, wv[3], acc[q]);
        }
    }

    const float a1c = a[c];
    const float a2c = a[64 + c];
    #pragma unroll
    for (int q = 0; q < 4; ++q) {
        float v1 = acc[q] * a1c;
        float v2 = acc[q] * a2c;
        #pragma unroll
        for (int m = 32; m; m >>= 1) {
            v1 += __shfl_xor(v1, m, 64);
            v2 += __shfl_xor(v2, m, 64);
        }
        if (c == 0) {
            s1[i0 + 4 * w + q] = v1;
            s2[i0 + 4 * w + q] = v2;
        }
    }

    // A-fragment-swizzled store (q=0..3 -> e0..e0+3, same fragment word)
    const int i   = i0 + 4 * w;
    const int jt  = i >> 5;
    const int sub = (i >> 3) & 3;
    const int e0  = i & 7;           // 0 or 4
    ushort4 pk;
    pk.x = f2bf(acc[0]); pk.y = f2bf(acc[1]);
    pk.z = f2bf(acc[2]); pk.w = f2bf(acc[3]);
    *(ushort4*)&Asw[((size_t)(c >> 4) * 256 + jt) * 512 + ((c & 15) + 16 * sub) * 8 + e0] = pk;
}

// ---------------------------------------------------------------------------
// Kernel 2: fused masked-softmax attention. Barrier-free, LDS-free.
//   Each wave: 32-row i-tile x 512-col j-split. Mask tile 16x128 = one dense
//   256 B load per row-half per superstep; __shfl redistributes words into
//   the B-fragment lane layout (lane l: row i=l&15, j=(l>>4)*8+e).
//   4096 wave-tasks = 1024 blocks x 4 waves.
// ---------------------------------------------------------------------------
__global__ __launch_bounds__(256) void k2_attn(
    const unsigned* __restrict__ mask, const unsigned short* __restrict__ Asw,
    const float* __restrict__ s1g, const float* __restrict__ s2g,
    float* __restrict__ Opart, float* __restrict__ lpart)
{
    const int tid   = threadIdx.x;
    const int l     = tid & 63;
    const int w     = tid >> 6;
    const int task  = blockIdx.x * 4 + w;      // 0..4095
    const int it    = task >> 4;               // 0..255
    const int split = task & 15;
    const int i0    = it * 32;
    const int jbase = split * JSPLIT;
    const int jb32  = jbase >> 5;

    const int il  = l & 15;
    const int kg  = l >> 4;                    // 0..3
    const int kg8 = kg * 8;

    const float s1a = s1g[i0 + il];
    const float s1b = s1g[i0 + 16 + il];

    const unsigned* mrA = mask + (size_t)(i0 + il) * NW32 + jb32 + kg;
    const unsigned* mrB = mrA + (size_t)16 * NW32;

    f32x4 a00 = {0,0,0,0}, a01 = {0,0,0,0}, a10 = {0,0,0,0}, a11 = {0,0,0,0};
    f32x4 a20 = {0,0,0,0}, a21 = {0,0,0,0}, a30 = {0,0,0,0}, a31 = {0,0,0,0};
    float rsA = 0.f, rsB = 0.f;

#define SC1(S1, S2c, BIT) ((BIT) ? __expf(fmaxf((S1) + (S2c), ALPHA * ((S1) + (S2c)))) : 0.f)

    for (int ss = 0; ss < JSPLIT / 128; ++ss) {   // 4 supersteps
        const int j0 = jbase + ss * 128;
        const unsigned mwA = mrA[ss * 4];   // word (jb32 + ss*4 + kg) of row i0+il
        const unsigned mwB = mrB[ss * 4];

        #pragma unroll
        for (int ks = 0; ks < 4; ++ks) {
            const unsigned bA = (__shfl(mwA, il + 16 * ks, 64) >> kg8) & 0xffu;
            const unsigned bB = (__shfl(mwB, il + 16 * ks, 64) >> kg8) & 0xffu;

            const float* sp = s2g + j0 + ks * 32 + kg8;
            const float4 sa = *(const float4*)sp;
            const float4 sb = *(const float4*)(sp + 4);

            float p0 = SC1(s1a, sa.x, bA & 1u),        p1 = SC1(s1a, sa.y, (bA >> 1) & 1u);
            float p2 = SC1(s1a, sa.z, (bA >> 2) & 1u), p3 = SC1(s1a, sa.w, (bA >> 3) & 1u);
            float p4 = SC1(s1a, sb.x, (bA >> 4) & 1u), p5 = SC1(s1a, sb.y, (bA >> 5) & 1u);
            float p6 = SC1(s1a, sb.z, (bA >> 6) & 1u), p7 = SC1(s1a, sb.w, (bA >> 7) & 1u);
            float q0 = SC1(s1b, sa.x, bB & 1u),        q1 = SC1(s1b, sa.y, (bB >> 1) & 1u);
            float q2 = SC1(s1b, sa.z, (bB >> 2) & 1u), q3 = SC1(s1b, sa.w, (bB >> 3) & 1u);
            float q4 = SC1(s1b, sb.x, (bB >> 4) & 1u), q5 = SC1(s1b, sb.y, (bB >> 5) & 1u);
            float q6 = SC1(s1b, sb.z, (bB >> 6) & 1u), q7 = SC1(s1b, sb.w, (bB >> 7) & 1u);

            rsA += ((p0 + p1) + (p2 + p3)) + ((p4 + p5) + (p6 + p7));
            rsB += ((q0 + q1) + (q2 + q3)) + ((q4 + q5) + (q6 + q7));

            uint4 wa, wb;
            asm("v_cvt_pk_bf16_f32 %0, %1, %2" : "=v"(wa.x) : "v"(p0), "v"(p1));
            asm("v_cvt_pk_bf16_f32 %0, %1, %2" : "=v"(wa.y) : "v"(p2), "v"(p3));
            asm("v_cvt_pk_bf16_f32 %0, %1, %2" : "=v"(wa.z) : "v"(p4), "v"(p5));
            asm("v_cvt_pk_bf16_f32 %0, %1, %2" : "=v"(wa.w) : "v"(p6), "v"(p7));
            asm("v_cvt_pk_bf16_f32 %0, %1, %2" : "=v"(wb.x) : "v"(q0), "v"(q1));
            asm("v_cvt_pk_bf16_f32 %0, %1, %2" : "=v"(wb.y) : "v"(q2), "v"(q3));
            asm("v_cvt_pk_bf16_f32 %0, %1, %2" : "=v"(wb.z) : "v"(q4), "v"(q5));
            asm("v_cvt_pk_bf16_f32 %0, %1, %2" : "=v"(wb.w) : "v"(q6), "v"(q7));
            const bf16x8 BA = __builtin_bit_cast(bf16x8, wa);
            const bf16x8 BB = __builtin_bit_cast(bf16x8, wb);

            // dense 1 KB A-loads (L2-hot), q-group stride 256*512 shorts
            const unsigned short* Ap =
                Asw + ((size_t)((j0 + ks * 32) >> 5)) * 512 + l * 8;
            const bf16x8 A0 = *(const bf16x8*)(Ap);
            const bf16x8 A1 = *(const bf16x8*)(Ap + 131072);
            const bf16x8 A2 = *(const bf16x8*)(Ap + 262144);
            const bf16x8 A3 = *(const bf16x8*)(Ap + 393216);

            a00 = __builtin_amdgcn_mfma_f32_16x16x32_bf16(A0, BA, a00, 0, 0, 0);
            a01 = __builtin_amdgcn_mfma_f32_16x16x32_bf16(A0, BB, a01, 0, 0, 0);
            a10 = __builtin_amdgcn_mfma_f32_16x16x32_bf16(A1, BA, a10, 0, 0, 0);
            a11 = __builtin_amdgcn_mfma_f32_16x16x32_bf16(A1, BB, a11, 0, 0, 0);
            a20 = __builtin_amdgcn_mfma_f32_16x16x32_bf16(A2, BA, a20, 0, 0, 0);
            a21 = __builtin_amdgcn_mfma_f32_16x16x32_bf16(A2, BB, a21, 0, 0, 0);
            a30 = __builtin_amdgcn_mfma_f32_16x16x32_bf16(A3, BA, a30, 0, 0, 0);
            a31 = __builtin_amdgcn_mfma_f32_16x16x32_bf16(A3, BB, a31, 0, 0, 0);
        }
    }
#undef SC1

    // row-sums: lanes {il, il+16, il+32, il+48} hold partials of row i0(+16)+il
    rsA += __shfl_xor(rsA, 16, 64);
    rsA += __shfl_xor(rsA, 32, 64);
    rsB += __shfl_xor(rsB, 16, 64);
    rsB += __shfl_xor(rsB, 32, 64);
    if (l < 16) {
        lpart[(size_t)split * NN + i0 + il]      = rsA;
        lpart[(size_t)split * NN + i0 + 16 + il] = rsB;
    }

    // numerator partials: a<q><h>[r] = out^T[n=q*16+kg*4+r][i=i0+h*16+il]
    const int nn = kg * 4;
    float* OA = Opart + ((size_t)split * NN + i0 + il) * OUTF + nn;
    float* OB = OA + (size_t)16 * OUTF;
    *(float4*)(OA)      = *(float4*)&a00;
    *(float4*)(OA + 16) = *(float4*)&a10;
    *(float4*)(OA + 32) = *(float4*)&a20;
    *(float4*)(OA + 48) = *(float4*)&a30;
    *(float4*)(OB)      = *(float4*)&a01;
    *(float4*)(OB + 16) = *(float4*)&a11;
    *(float4*)(OB + 32) = *(float4*)&a21;
    *(float4*)(OB + 48) = *(float4*)&a31;
}

// ---------------------------------------------------------------------------
// Kernel 3: combine the 16 j-split partials and normalize.
// ---------------------------------------------------------------------------
__global__ __launch_bounds__(256) void k3_combine(
    const float* __restrict__ Opart, const float* __restrict__ lpart,
    float* __restrict__ out)
{
    const int f4 = blockIdx.x * 256 + threadIdx.x;   // 0..131071
    const int i  = f4 >> 4;

    float4 r = {0.f, 0.f, 0.f, 0.f};
    float  lsum = 0.f;
    #pragma unroll
    for (int s = 0; s < NSPLIT; ++s) {
        float4 o = *(const float4*)&Opart[(size_t)s * NN * OUTF + (size_t)f4 * 4];
        r.x += o.x; r.y += o.y; r.z += o.z; r.w += o.w;
        lsum += lpart[(size_t)s * NN + i];
    }
    float inv = 1.0f / lsum;
    r.x *= inv; r.y *= inv; r.z *= inv; r.w *= inv;
    *(float4*)&out[(size_t)f4 * 4] = r;
}

extern "C" void kernel_launch(void* const* d_in, const int* in_sizes, int n_in,
                              void* d_out, int out_size, void* d_ws, size_t ws_size,
                              hipStream_t stream) {
    const float* x   = (const float*)d_in[0];
    const int*   adj = (const int*)d_in[1];
    const float* W   = (const float*)d_in[2];
    const float* a   = (const float*)d_in[3];
    float* out = (float*)d_out;

    char* ws = (char*)d_ws;
    unsigned short* Asw = (unsigned short*)ws;                      // 1 MB
    float* s1    = (float*)(ws + (1 << 20));                        // 32 KB
    float* s2    = (float*)(ws + (1 << 20) + 32768);                // 32 KB
    float* lpart = (float*)(ws + (1 << 20) + 65536);                // 512 KB
    unsigned* mask = (unsigned*)(ws + (1 << 20) + 65536 + 524288);  // 8 MB
    float* Opart = (float*)(ws + (1 << 20) + 65536 + 524288 + (8 << 20)); // 32 MB

    k0_mask<<<8192, 256, 0, stream>>>(adj, mask);
    k1_gemm<<<512, 256, 0, stream>>>(x, W, a, Asw, s1, s2);
    k2_attn<<<1024, 256, 0, stream>>>(mask, Asw, s1, s2, Opart, lpart);
    k3_combine<<<512, 256, 0, stream>>>(Opart, lpart, out);
}

// Round 5
// 97.103 us; speedup vs baseline: 1.5393x; 1.1943x over previous
//
#include <hip/hip_runtime.h>
#include <cstdint>
#include <cstddef>

#define NN 8192
#define INF 512
#define OUTF 64
#define ALPHA 0.2f
#define NSPLIT 16
#define JSPLIT (NN / NSPLIT)   // 512
#define NW32 (NN / 32)         // 256 mask words per row
#define GEMM_BLOCKS 512

typedef short bf16x8 __attribute__((ext_vector_type(8)));
typedef float f32x4 __attribute__((ext_vector_type(4)));

static __device__ inline unsigned short f2bf(float f) {
    unsigned u = __builtin_bit_cast(unsigned, f);
    unsigned r = (u + 0x7FFFu + ((u >> 16) & 1u)) >> 16;
    return (unsigned short)r;
}

// ---------------------------------------------------------------------------
// Kernel 01 (fused): blocks 0..511 = GEMM (LDS-free, scalar-x), blocks
// 512..8703 = adj->bitmask pack (one adj row per block, LDS-swizzle coalesce).
// GEMM blocks dispatch first and hide under the 268 MB mask stream.
// ---------------------------------------------------------------------------
__global__ __launch_bounds__(256) void k01_fused(
    const float* __restrict__ x, const int* __restrict__ adj,
    const float* __restrict__ W, const float* __restrict__ a,
    unsigned short* __restrict__ Asw, float* __restrict__ s1,
    float* __restrict__ s2, unsigned* __restrict__ mask)
{
    __shared__ int ldsbuf[8192];   // 32 KB (mask path only)
    const int tid = threadIdx.x;

    if (blockIdx.x >= GEMM_BLOCKS) {
        // ---------------- mask path: one adj row ----------------
        const int row = blockIdx.x - GEMM_BLOCKS;
        const int* arow = adj + (size_t)row * NN;

        // phase 1: fully-coalesced loads (1 KB/wave-instr), swizzled LDS store
        #pragma unroll
        for (int k = 0; k < 8; ++k) {
            const int i = k * 1024 + tid * 4;
            int4 v = *(const int4*)(arow + i);
            const int p = i ^ (((i >> 7) & 7) << 2);
            *(int4*)&ldsbuf[p] = v;
        }
        __syncthreads();

        // phase 2: each thread packs 32 consecutive ints -> one mask word
        unsigned m = 0;
        #pragma unroll
        for (int k = 0; k < 8; ++k) {
            const int i2 = tid * 32 + k * 4;
            const int p2 = i2 ^ (((i2 >> 7) & 7) << 2);
            int4 v = *(const int4*)&ldsbuf[p2];
            m |= (v.x != 0 ? 1u : 0u) << (4 * k);
            m |= (v.y != 0 ? 1u : 0u) << (4 * k + 1);
            m |= (v.z != 0 ? 1u : 0u) << (4 * k + 2);
            m |= (v.w != 0 ? 1u : 0u) << (4 * k + 3);
        }
        mask[(size_t)row * NW32 + tid] = m;
        return;
    }

    // ---------------- GEMM path: 16 rows of Wh per block ----------------
    const int i0 = blockIdx.x * 16;
    const int w  = __builtin_amdgcn_readfirstlane(tid >> 6);  // wave-uniform
    const int c  = tid & 63;

    // x rows for this wave are wave-uniform -> scalar loads, no LDS
    const float* xr = x + (size_t)(i0 + 4 * w) * INF;
    const float* Wc = W + c;
    float acc[4] = {0.f, 0.f, 0.f, 0.f};

    #pragma unroll 4
    for (int kk = 0; kk < 128; ++kk) {
        const float4 x0 = *(const float4*)(xr + 0 * INF + kk * 4);
        const float4 x1 = *(const float4*)(xr + 1 * INF + kk * 4);
        const float4 x2 = *(const float4*)(xr + 2 * INF + kk * 4);
        const float4 x3 = *(const float4*)(xr + 3 * INF + kk * 4);
        const float w0 = Wc[(kk * 4 + 0) * OUTF];
        const float w1 = Wc[(kk * 4 + 1) * OUTF];
        const float w2 = Wc[(kk * 4 + 2) * OUTF];
        const float w3 = Wc[(kk * 4 + 3) * OUTF];
        acc[0] = fmaf(x0.x, w0, fmaf(x0.y, w1, fmaf(x0.z, w2, fmaf(x0.w, w3, acc[0]))));
        acc[1] = fmaf(x1.x, w0, fmaf(x1.y, w1, fmaf(x1.z, w2, fmaf(x1.w, w3, acc[1]))));
        acc[2] = fmaf(x2.x, w0, fmaf(x2.y, w1, fmaf(x2.z, w2, fmaf(x2.w, w3, acc[2]))));
        acc[3] = fmaf(x3.x, w0, fmaf(x3.y, w1, fmaf(x3.z, w2, fmaf(x3.w, w3, acc[3]))));
    }

    const float a1c = a[c];
    const float a2c = a[64 + c];
    #pragma unroll
    for (int q = 0; q < 4; ++q) {
        float v1 = acc[q] * a1c;
        float v2 = acc[q] * a2c;
        #pragma unroll
        for (int m = 32; m; m >>= 1) {
            v1 += __shfl_xor(v1, m, 64);
            v2 += __shfl_xor(v2, m, 64);
        }
        if (c == 0) {
            s1[i0 + 4 * w + q] = v1;
            s2[i0 + 4 * w + q] = v2;
        }
    }

    // A-fragment-swizzled store (verified layout, unchanged)
    const int i   = i0 + 4 * w;
    const int jt  = i >> 5;
    const int sub = (i >> 3) & 3;
    const int e0  = i & 7;
    ushort4 pk;
    pk.x = f2bf(acc[0]); pk.y = f2bf(acc[1]);
    pk.z = f2bf(acc[2]); pk.w = f2bf(acc[3]);
    *(ushort4*)&Asw[((size_t)(c >> 4) * 256 + jt) * 512 + ((c & 15) + 16 * sub) * 8 + e0] = pk;
}

// ---------------------------------------------------------------------------
// Kernel 2: fused masked-softmax attention. Barrier-free, LDS-free.
//   Wave task = 32-row i-tile x 512-col j-split. All 8 mask words preloaded;
//   A-fragments + s2 software-pipelined one step ahead (16 steps, unrolled).
// ---------------------------------------------------------------------------
__global__ __launch_bounds__(256) void k2_attn(
    const unsigned* __restrict__ mask, const unsigned short* __restrict__ Asw,
    const float* __restrict__ s1g, const float* __restrict__ s2g,
    float* __restrict__ Opart, float* __restrict__ lpart)
{
    const int tid   = threadIdx.x;
    const int l     = tid & 63;
    const int w     = tid >> 6;
    const int task  = blockIdx.x * 4 + w;      // 0..4095
    const int it    = task >> 4;               // 0..255
    const int split = task & 15;
    const int i0    = it * 32;
    const int jbase = split * JSPLIT;
    const int jb32  = jbase >> 5;

    const int il  = l & 15;
    const int kg  = l >> 4;
    const int kg8 = kg * 8;

    const float s1a = s1g[i0 + il];
    const float s1b = s1g[i0 + 16 + il];

    // preload all 8 mask words for this task (4 supersteps x 2 row-halves)
    const unsigned* mbase = mask + (size_t)(i0 + il) * NW32 + jb32 + kg;
    unsigned mA[4], mB[4];
    #pragma unroll
    for (int ss = 0; ss < 4; ++ss) {
        mA[ss] = mbase[ss * 4];
        mB[ss] = mbase[(size_t)16 * NW32 + ss * 4];
    }

    f32x4 a00 = {0,0,0,0}, a01 = {0,0,0,0}, a10 = {0,0,0,0}, a11 = {0,0,0,0};
    f32x4 a20 = {0,0,0,0}, a21 = {0,0,0,0}, a30 = {0,0,0,0}, a31 = {0,0,0,0};
    float rsA = 0.f, rsB = 0.f;

    // step t (0..15): j-chunk jbase + t*32
    const unsigned short* A8 = Asw + (size_t)(jb32 + 0) * 512 + l * 8;
    const float* sp0 = s2g + jbase + kg8;

    bf16x8 A0c = *(const bf16x8*)(A8);
    bf16x8 A1c = *(const bf16x8*)(A8 + 131072);
    bf16x8 A2c = *(const bf16x8*)(A8 + 262144);
    bf16x8 A3c = *(const bf16x8*)(A8 + 393216);
    float4 sac = *(const float4*)(sp0);
    float4 sbc = *(const float4*)(sp0 + 4);

#define SC1(S1, S2c, BIT) ((BIT) ? __expf(fmaxf((S1) + (S2c), ALPHA * ((S1) + (S2c)))) : 0.f)

    #pragma unroll
    for (int t = 0; t < 16; ++t) {
        // prefetch step t+1 (last step reloads itself; harmless)
        const int tn = (t < 15) ? t + 1 : t;
        const unsigned short* An = Asw + (size_t)(jb32 + tn) * 512 + l * 8;
        bf16x8 A0n = *(const bf16x8*)(An);
        bf16x8 A1n = *(const bf16x8*)(An + 131072);
        bf16x8 A2n = *(const bf16x8*)(An + 262144);
        bf16x8 A3n = *(const bf16x8*)(An + 393216);
        const float* spn = s2g + jbase + tn * 32 + kg8;
        float4 san = *(const float4*)(spn);
        float4 sbn = *(const float4*)(spn + 4);

        const int ss = t >> 2, ks = t & 3;
        const unsigned bA = (__shfl(mA[ss], il + 16 * ks, 64) >> kg8) & 0xffu;
        const unsigned bB = (__shfl(mB[ss], il + 16 * ks, 64) >> kg8) & 0xffu;

        float p0 = SC1(s1a, sac.x, bA & 1u),        p1 = SC1(s1a, sac.y, (bA >> 1) & 1u);
        float p2 = SC1(s1a, sac.z, (bA >> 2) & 1u), p3 = SC1(s1a, sac.w, (bA >> 3) & 1u);
        float p4 = SC1(s1a, sbc.x, (bA >> 4) & 1u), p5 = SC1(s1a, sbc.y, (bA >> 5) & 1u);
        float p6 = SC1(s1a, sbc.z, (bA >> 6) & 1u), p7 = SC1(s1a, sbc.w, (bA >> 7) & 1u);
        float q0 = SC1(s1b, sac.x, bB & 1u),        q1 = SC1(s1b, sac.y, (bB >> 1) & 1u);
        float q2 = SC1(s1b, sac.z, (bB >> 2) & 1u), q3 = SC1(s1b, sac.w, (bB >> 3) & 1u);
        float q4 = SC1(s1b, sbc.x, (bB >> 4) & 1u), q5 = SC1(s1b, sbc.y, (bB >> 5) & 1u);
        float q6 = SC1(s1b, sbc.z, (bB >> 6) & 1u), q7 = SC1(s1b, sbc.w, (bB >> 7) & 1u);

        rsA += ((p0 + p1) + (p2 + p3)) + ((p4 + p5) + (p6 + p7));
        rsB += ((q0 + q1) + (q2 + q3)) + ((q4 + q5) + (q6 + q7));

        uint4 wa, wb;
        asm("v_cvt_pk_bf16_f32 %0, %1, %2" : "=v"(wa.x) : "v"(p0), "v"(p1));
        asm("v_cvt_pk_bf16_f32 %0, %1, %2" : "=v"(wa.y) : "v"(p2), "v"(p3));
        asm("v_cvt_pk_bf16_f32 %0, %1, %2" : "=v"(wa.z) : "v"(p4), "v"(p5));
        asm("v_cvt_pk_bf16_f32 %0, %1, %2" : "=v"(wa.w) : "v"(p6), "v"(p7));
        asm("v_cvt_pk_bf16_f32 %0, %1, %2" : "=v"(wb.x) : "v"(q0), "v"(q1));
        asm("v_cvt_pk_bf16_f32 %0, %1, %2" : "=v"(wb.y) : "v"(q2), "v"(q3));
        asm("v_cvt_pk_bf16_f32 %0, %1, %2" : "=v"(wb.z) : "v"(q4), "v"(q5));
        asm("v_cvt_pk_bf16_f32 %0, %1, %2" : "=v"(wb.w) : "v"(q6), "v"(q7));
        const bf16x8 BA = __builtin_bit_cast(bf16x8, wa);
        const bf16x8 BB = __builtin_bit_cast(bf16x8, wb);

        a00 = __builtin_amdgcn_mfma_f32_16x16x32_bf16(A0c, BA, a00, 0, 0, 0);
        a01 = __builtin_amdgcn_mfma_f32_16x16x32_bf16(A0c, BB, a01, 0, 0, 0);
        a10 = __builtin_amdgcn_mfma_f32_16x16x32_bf16(A1c, BA, a10, 0, 0, 0);
        a11 = __builtin_amdgcn_mfma_f32_16x16x32_bf16(A1c, BB, a11, 0, 0, 0);
        a20 = __builtin_amdgcn_mfma_f32_16x16x32_bf16(A2c, BA, a20, 0, 0, 0);
        a21 = __builtin_amdgcn_mfma_f32_16x16x32_bf16(A2c, BB, a21, 0, 0, 0);
        a30 = __builtin_amdgcn_mfma_f32_16x16x32_bf16(A3c, BA, a30, 0, 0, 0);
        a31 = __builtin_amdgcn_mfma_f32_16x16x32_bf16(A3c, BB, a31, 0, 0, 0);

        A0c = A0n; A1c = A1n; A2c = A2n; A3c = A3n;
        sac = san; sbc = sbn;
    }
#undef SC1

    rsA += __shfl_xor(rsA, 16, 64);
    rsA += __shfl_xor(rsA, 32, 64);
    rsB += __shfl_xor(rsB, 16, 64);
    rsB += __shfl_xor(rsB, 32, 64);
    if (l < 16) {
        lpart[(size_t)split * NN + i0 + il]      = rsA;
        lpart[(size_t)split * NN + i0 + 16 + il] = rsB;
    }

    const int nn = kg * 4;
    float* OA = Opart + ((size_t)split * NN + i0 + il) * OUTF + nn;
    float* OB = OA + (size_t)16 * OUTF;
    *(float4*)(OA)      = *(float4*)&a00;
    *(float4*)(OA + 16) = *(float4*)&a10;
    *(float4*)(OA + 32) = *(float4*)&a20;
    *(float4*)(OA + 48) = *(float4*)&a30;
    *(float4*)(OB)      = *(float4*)&a01;
    *(float4*)(OB + 16) = *(float4*)&a11;
    *(float4*)(OB + 32) = *(float4*)&a21;
    *(float4*)(OB + 48) = *(float4*)&a31;
}

// ---------------------------------------------------------------------------
// Kernel 3: combine the 16 j-split partials and normalize.
// ---------------------------------------------------------------------------
__global__ __launch_bounds__(256) void k3_combine(
    const float* __restrict__ Opart, const float* __restrict__ lpart,
    float* __restrict__ out)
{
    const int f4 = blockIdx.x * 256 + threadIdx.x;   // 0..131071
    const int i  = f4 >> 4;

    float4 r = {0.f, 0.f, 0.f, 0.f};
    float  lsum = 0.f;
    #pragma unroll
    for (int s = 0; s < NSPLIT; ++s) {
        float4 o = *(const float4*)&Opart[(size_t)s * NN * OUTF + (size_t)f4 * 4];
        r.x += o.x; r.y += o.y; r.z += o.z; r.w += o.w;
        lsum += lpart[(size_t)s * NN + i];
    }
    float inv = 1.0f / lsum;
    r.x *= inv; r.y *= inv; r.z *= inv; r.w *= inv;
    *(float4*)&out[(size_t)f4 * 4] = r;
}

extern "C" void kernel_launch(void* const* d_in, const int* in_sizes, int n_in,
                              void* d_out, int out_size, void* d_ws, size_t ws_size,
                              hipStream_t stream) {
    const float* x   = (const float*)d_in[0];
    const int*   adj = (const int*)d_in[1];
    const float* W   = (const float*)d_in[2];
    const float* a   = (const float*)d_in[3];
    float* out = (float*)d_out;

    char* ws = (char*)d_ws;
    unsigned short* Asw = (unsigned short*)ws;                      // 1 MB
    float* s1    = (float*)(ws + (1 << 20));                        // 32 KB
    float* s2    = (float*)(ws + (1 << 20) + 32768);                // 32 KB
    float* lpart = (float*)(ws + (1 << 20) + 65536);                // 512 KB
    unsigned* mask = (unsigned*)(ws + (1 << 20) + 65536 + 524288);  // 8 MB
    float* Opart = (float*)(ws + (1 << 20) + 65536 + 524288 + (8 << 20)); // 32 MB

    k01_fused<<<GEMM_BLOCKS + NN, 256, 0, stream>>>(x, adj, W, a, Asw, s1, s2, mask);
    k2_attn<<<1024, 256, 0, stream>>>(mask, Asw, s1, s2, Opart, lpart);
    k3_combine<<<512, 256, 0, stream>>>(Opart, lpart, out);
}